// Round 17
// baseline (67.633 us; speedup 1.0000x reference)
//
#include <hip/hip_runtime.h>
#include <hip/hip_bf16.h>

#define B_ 4
#define L_ 32768
#define C_ 64
#define K_ 7
#define T_ 16378              // (L - 2K)/2 + 1
#define M_ (B_*T_)            // 65512 rows
#define TJ 16                 // output positions per j-tile
#define IT 4                  // j-tiles per kA block
#define NJB 256               // grid.x of kA  (NJB*IT*TJ = 16384 >= T_)
#define NBLKA (B_*NJB)        // 1024 partial sets
#define NBZ 512               // kZ blocks (x128 rows)
#define NBE 512               // kE blocks (x128 rows)

// workspace layout in floats
#define OF_WB   0                        // Wb: 28672 ushorts = 14336 floats
#define OF_WB2  14336                    // Wb2: 4096 ushorts = 2048 floats
#define OF_Y    16384                    // y bf16: M_*64 ushorts = M_*32 floats
#define OF_PS1  (OF_Y + M_*32)           // [c][NBLKA]
#define OF_PQ1  (OF_PS1 + 64*NBLKA)
#define OF_PS2  (OF_PQ1 + 64*NBLKA)      // [c][NBZ]
#define OF_PQ2  (OF_PS2 + 64*NBZ)
#define OF_C1   (OF_PQ2 + 64*NBZ)        // A1[64], BB1[64]

typedef __attribute__((ext_vector_type(8))) short short8;
typedef __attribute__((ext_vector_type(4))) float f32x4;

__device__ __forceinline__ unsigned cvt_pk_bf16(float a, float b) {
    unsigned r;
    asm("v_cvt_pk_bf16_f32 %0, %1, %2" : "=v"(r) : "v"(a), "v"(b));
    return r;   // lo = bf16(a), hi = bf16(b)
}

__device__ __forceinline__ float fast_tanh(float x) {
    float e = __builtin_amdgcn_exp2f(x * 2.885390082f);   // 2*log2(e)
    return __builtin_fmaf(-2.f, __builtin_amdgcn_rcpf(1.f + e), 1.f);
}

__device__ __forceinline__ float gelu_tanh(float v) {
    float u = 0.7978845608028654f * (v + 0.044715f * v * v * v);
    return 0.5f * v * (1.f + fast_tanh(u));
}

__device__ __forceinline__ float bfu(ushort h) {
    union { unsigned u; float f; } v; v.u = ((unsigned)h) << 16; return v.f;
}
__device__ __forceinline__ float bflo(unsigned p) {
    union { unsigned u; float f; } v; v.u = p << 16; return v.f;
}

// repack weights (d,c,kk) -> B-fragments Wb[(kt*28+nt)*64 + lane][j] (bf16)
__global__ void kPb(const float* __restrict__ w, ushort* __restrict__ Wb) {
    int i = blockIdx.x * 256 + threadIdx.x;   // 28672 total
    if (i < 28672) {
        int j = i & 7;
        int l = (i >> 3) & 63;
        int q = i >> 9;            // kt*28 + nt
        int nt = q % 28, kt = q / 28;
        int k = kt * 32 + 8 * (l >> 4) + j;       // channel c
        int n = nt * 16 + (l & 15);
        int d = n / 7, kk = n - 7 * d;
        Wb[i] = (ushort)(cvt_pk_bf16(w[(d * 64 + k) * 7 + kk], 0.f) & 0xffffu);
    }
}

// fused: dyn-weight GEMM (MFMA) + tanh + taps + residual + BN1 partials.
// BARRIER-FREE: wave w owns channels d in [16w,16w+16); per-wave private LDS.
__global__ __launch_bounds__(256, 4) void kA(const float* __restrict__ x,
                                             const ushort* __restrict__ Wb,
                                             ushort* __restrict__ y,
                                             float* __restrict__ ps,
                                             float* __restrict__ pq) {
    // per-wave: gw[112][72B] (8064 B, 8-aligned rows) ; xpw[22][17]u32 (1496 B)
    __shared__ char sm[4 * 8064 + 4 * 1496];

    const int tid = threadIdx.x;
    const int w = tid >> 6, l = tid & 63;
    char* gw  = sm + w * 8064;
    char* xpw = sm + 4 * 8064 + w * 1496;
    const int b = blockIdx.y;
    const float* xb = x + b * (L_ * 64);

    short8 wreg[7][2];
    #pragma unroll
    for (int i = 0; i < 7; ++i) {
        wreg[i][0] = *(const short8*)&Wb[((7 * w + i) * 64 + l) * 8];
        wreg[i][1] = *(const short8*)&Wb[((28 + 7 * w + i) * 64 + l) * 8];
    }

    const int cl = l & 15, r0 = 4 * (l >> 4);
    const int g = l >> 4, dp = l & 15;
    float S = 0.f, Q = 0.f;

    for (int it = 0; it < IT; ++it) {
        const int jt = blockIdx.x * IT + it;
        const int j0 = jt * TJ;
        const int xrow0 = 2 * j0;
        const bool tail = (jt == NJB * IT - 1);

        // ---- stage tap slice: items = (rowpair rp, channel-pair cp), float2 loads ----
        #pragma unroll
        for (int q = 0; q < 3; ++q) {
            int item = q * 64 + l;             // 0..175 used (22 rp * 8 cp)
            if (q < 2 || l < 48) {
                int rp = item >> 3, cp = item & 7;
                int ra = xrow0 + 2 * rp, rb = ra + 1;
                if (tail) { ra = min(ra, L_ - 1); rb = min(rb, L_ - 1); }
                float2 va = *(const float2*)(xb + ra * 64 + 16 * w + 2 * cp);
                float2 vb = *(const float2*)(xb + rb * 64 + 16 * w + 2 * cp);
                uint2 wv;
                wv.x = cvt_pk_bf16(va.x, vb.x);
                wv.y = cvt_pk_bf16(va.y, vb.y);
                *(uint2*)(xpw + rp * 68 + cp * 8) = wv;
            }
        }

        short8 afr[2][2];
        #pragma unroll
        for (int mt = 0; mt < 2; ++mt)
            #pragma unroll
            for (int kt = 0; kt < 2; ++kt) {
                int row = xrow0 + 12 + mt * 16 + cl;
                if (tail) row = min(row, L_ - 1);
                const float* pr = xb + row * 64 + kt * 32 + (l >> 4) * 8;
                float4 v0 = *(const float4*)pr;
                float4 v1 = *(const float4*)(pr + 4);
                uint4 u;
                u.x = cvt_pk_bf16(v0.x, v0.y);
                u.y = cvt_pk_bf16(v0.z, v0.w);
                u.z = cvt_pk_bf16(v1.x, v1.y);
                u.w = cvt_pk_bf16(v1.z, v1.w);
                afr[mt][kt] = *(short8*)&u;
            }

        #pragma unroll
        for (int i = 0; i < 7; ++i) {
            f32x4 acc0 = {0.f, 0.f, 0.f, 0.f};
            f32x4 acc1 = {0.f, 0.f, 0.f, 0.f};
            acc0 = __builtin_amdgcn_mfma_f32_16x16x32_bf16(afr[0][0], wreg[i][0], acc0, 0, 0, 0);
            acc0 = __builtin_amdgcn_mfma_f32_16x16x32_bf16(afr[0][1], wreg[i][1], acc0, 0, 0, 0);
            acc1 = __builtin_amdgcn_mfma_f32_16x16x32_bf16(afr[1][0], wreg[i][0], acc1, 0, 0, 0);
            acc1 = __builtin_amdgcn_mfma_f32_16x16x32_bf16(afr[1][1], wreg[i][1], acc1, 0, 0, 0);
            char* base = gw + (i * 16 + cl) * 72 + r0 * 2;
            *(unsigned*)(base)      = cvt_pk_bf16(fast_tanh(acc0[0]), fast_tanh(acc0[1]));
            *(unsigned*)(base + 4)  = cvt_pk_bf16(fast_tanh(acc0[2]), fast_tanh(acc0[3]));
            *(unsigned*)(base + 32) = cvt_pk_bf16(fast_tanh(acc1[0]), fast_tanh(acc1[1]));
            *(unsigned*)(base + 36) = cvt_pk_bf16(fast_tanh(acc1[2]), fast_tanh(acc1[3]));
        }

        #pragma unroll
        for (int p = 0; p < 2; ++p) {
            const int jj0 = 2 * g + 8 * p;
            unsigned xv[8];
            #pragma unroll
            for (int k2 = 0; k2 < 8; ++k2)
                xv[k2] = *(const unsigned*)((const char*)xpw + (jj0 + k2) * 68 + dp * 4);
            float acc0 = bflo(xv[6]);
            float acc1 = bflo(xv[7]);
            const char* gb = gw + dp * 504 + jj0 * 4;
            #pragma unroll
            for (int kk = 0; kk < K_; ++kk) {
                uint2 gp = *(const uint2*)(gb + kk * 72);
                asm("v_dot2_f32_bf16 %0, %1, %2, %0" : "+v"(acc0) : "v"(xv[kk]),     "v"(gp.x));
                asm("v_dot2_f32_bf16 %0, %1, %2, %0" : "+v"(acc1) : "v"(xv[kk + 1]), "v"(gp.y));
            }
            float o0 = __shfl_xor(acc0, 1);
            float o1 = __shfl_xor(acc1, 1);
            const int j = j0 + jj0;
            if (j < T_) {
                if ((dp & 1) == 0) {
                    *(unsigned*)((char*)y + (b * T_ + j) * 128 + (16 * w + dp) * 2)     = cvt_pk_bf16(acc0, o0);
                    *(unsigned*)((char*)y + (b * T_ + j + 1) * 128 + (16 * w + dp) * 2) = cvt_pk_bf16(acc1, o1);
                }
                S += acc0 + acc1;
                Q += acc0 * acc0 + acc1 * acc1;
            }
        }
    }

    S += __shfl_xor(S, 16); S += __shfl_xor(S, 32);
    Q += __shfl_xor(Q, 16); Q += __shfl_xor(Q, 32);
    if (l < 16) {
        int d = 16 * w + l;
        int blk = b * NJB + blockIdx.x;
        ps[d * NBLKA + blk] = S;
        pq[d * NBLKA + blk] = Q;
    }
}

// reduce transposed per-channel partials -> A1 = rstd*scale, BB1 = bias - mean*A1,
// and write this channel's 64 A1-folded w_conv B-fragments.
__global__ void kB(const float* __restrict__ ps, const float* __restrict__ pq,
                   float* __restrict__ A, float* __restrict__ BB,
                   const float* __restrict__ scale, const float* __restrict__ bias,
                   int nblk, float invN,
                   const float* __restrict__ wconv, ushort* __restrict__ Wb2) {
    const int c = blockIdx.x;
    const float* bs = ps + (long)c * nblk;
    const float* bq = pq + (long)c * nblk;
    float S = 0.f, Q = 0.f;
    for (int i = threadIdx.x; i < nblk; i += 256) {
        S += bs[i];
        Q += bq[i];
    }
    for (int o = 32; o > 0; o >>= 1) {
        S += __shfl_down(S, o);
        Q += __shfl_down(Q, o);
    }
    __shared__ float rs[4], rq[4];
    __shared__ float sa;
    if ((threadIdx.x & 63) == 0) { rs[threadIdx.x >> 6] = S; rq[threadIdx.x >> 6] = Q; }
    __syncthreads();
    if (threadIdx.x == 0) {
        S = rs[0] + rs[1] + rs[2] + rs[3];
        Q = rq[0] + rq[1] + rq[2] + rq[3];
        float m = S * invN;
        float var = Q * invN - m * m;
        float rstd = rsqrtf(var + 1e-5f);
        float a = rstd * scale[c];
        A[c] = a;
        BB[c] = bias[c] - m * a;
        sa = a;
    }
    if (Wb2 != nullptr) {
        __syncthreads();
        if (threadIdx.x < 64) {
            int e = threadIdx.x;
            float wv = sa * wconv[c * 64 + e];
            int kt = c >> 5, rem = c & 31, bslot = rem >> 3, j = rem & 7;
            int lane = bslot * 16 + (e & 15), nt = e >> 4;
            Wb2[(((kt * 4 + nt) * 64 + lane) << 3) + j] =
                (ushort)(cvt_pk_bf16(wv, 0.f) & 0xffffu);
        }
    }
}

// pass 2a: z' = y_bf16 @ Wb2, BN2 partials only — frags from global, no LDS staging
__global__ __launch_bounds__(256) void kZ(const ushort* __restrict__ y,
                                          const ushort* __restrict__ Wb2,
                                          float* __restrict__ ps2,
                                          float* __restrict__ pq2) {
    __shared__ float red[2][4][64];
    const int tid = threadIdx.x, w = tid >> 6, l = tid & 63;
    short8 bfr[4][2];
    #pragma unroll
    for (int nt = 0; nt < 4; ++nt)
        #pragma unroll
        for (int kt = 0; kt < 2; ++kt)
            bfr[nt][kt] = *(const short8*)&Wb2[((kt * 4 + nt) * 64 + l) * 8];

    float ss[4] = {0.f, 0.f, 0.f, 0.f}, qq[4] = {0.f, 0.f, 0.f, 0.f};
    #pragma unroll
    for (int g2 = 0; g2 < 2; ++g2) {
        long rowg = (long)blockIdx.x * 128 + g2 * 64 + w * 16 + (l & 15);
        short8 a0 = {0, 0, 0, 0, 0, 0, 0, 0};
        short8 a1 = {0, 0, 0, 0, 0, 0, 0, 0};
        if (rowg < M_) {
            const char* yr = (const char*)y + rowg * 128 + (l >> 4) * 16;
            a0 = *(const short8*)yr;
            a1 = *(const short8*)(yr + 64);
        }
        #pragma unroll
        for (int nt = 0; nt < 4; ++nt) {
            f32x4 acc = {0.f, 0.f, 0.f, 0.f};
            acc = __builtin_amdgcn_mfma_f32_16x16x32_bf16(a0, bfr[nt][0], acc, 0, 0, 0);
            acc = __builtin_amdgcn_mfma_f32_16x16x32_bf16(a1, bfr[nt][1], acc, 0, 0, 0);
            #pragma unroll
            for (int i = 0; i < 4; ++i) { ss[nt] += acc[i]; qq[nt] += acc[i] * acc[i]; }
        }
    }
    #pragma unroll
    for (int nt = 0; nt < 4; ++nt) {
        float s2 = ss[nt] + __shfl_xor(ss[nt], 16); s2 += __shfl_xor(s2, 32);
        float q2 = qq[nt] + __shfl_xor(qq[nt], 16); q2 += __shfl_xor(q2, 32);
        if (l < 16) { red[0][w][nt * 16 + l] = s2; red[1][w][nt * 16 + l] = q2; }
    }
    __syncthreads();
    if (tid < 64) {
        float S = red[0][0][tid] + red[0][1][tid] + red[0][2][tid] + red[0][3][tid];
        float Q = red[1][0][tid] + red[1][1][tid] + red[1][2][tid] + red[1][3][tid];
        ps2[tid * NBZ + blockIdx.x] = S;
        pq2[tid * NBZ + blockIdx.x] = Q;
    }
}

// pass 2b: redundant per-block BN2 coefficients (deterministic, no sync),
// then recompute z' -> LDS transpose -> coalesced fused epilogue.
__global__ __launch_bounds__(256) void kE(const ushort* __restrict__ y,
                                          const ushort* __restrict__ Wb2,
                                          const float* __restrict__ A1,
                                          const float* __restrict__ B1,
                                          const float* __restrict__ scale2,
                                          const float* __restrict__ bias2,
                                          const float* __restrict__ ps2,
                                          const float* __restrict__ pq2,
                                          float* __restrict__ out) {
    __shared__ float zs[64][68];     // padded, 17408 B
    __shared__ float cf[4][64];
    __shared__ float red[2][4][64];  // 2048 B
    const int tid = threadIdx.x, w = tid >> 6, l = tid & 63;

    // ---- redundant BN2 coefficient computation (identical in every block) ----
    {
        const float4* pv = (const float4*)(ps2 + l * NBZ + w * 128);
        const float4* qv = (const float4*)(pq2 + l * NBZ + w * 128);
        float S = 0.f, Q = 0.f;
        #pragma unroll 8
        for (int k = 0; k < 32; ++k) {
            float4 a4 = pv[k], b4 = qv[k];
            S += (a4.x + a4.y) + (a4.z + a4.w);
            Q += (b4.x + b4.y) + (b4.z + b4.w);
        }
        red[0][w][l] = S;
        red[1][w][l] = Q;
    }
    if (tid < 64)       cf[0][tid] = A1[tid];
    else if (tid < 128) cf[1][tid - 64] = B1[tid - 64];
    __syncthreads();
    if (tid < 64) {
        float S = red[0][0][tid] + red[0][1][tid] + red[0][2][tid] + red[0][3][tid];
        float Q = red[1][0][tid] + red[1][1][tid] + red[1][2][tid] + red[1][3][tid];
        const float invN = 1.f / (float)M_;
        float m = S * invN;
        float var = Q * invN - m * m;
        float rstd = rsqrtf(var + 1e-5f);
        float a = rstd * scale2[tid];
        cf[2][tid] = a;
        cf[3][tid] = bias2[tid] - m * a;
    }

    short8 bfr[4][2];
    #pragma unroll
    for (int nt = 0; nt < 4; ++nt)
        #pragma unroll
        for (int kt = 0; kt < 2; ++kt)
            bfr[nt][kt] = *(const short8*)&Wb2[((kt * 4 + nt) * 64 + l) * 8];

    #pragma unroll
    for (int g2 = 0; g2 < 2; ++g2) {
        const long row0 = (long)blockIdx.x * 128 + g2 * 64;
        long rowg = row0 + w * 16 + (l & 15);
        short8 a0 = {0, 0, 0, 0, 0, 0, 0, 0};
        short8 a1 = {0, 0, 0, 0, 0, 0, 0, 0};
        if (rowg < M_) {
            const char* yr = (const char*)y + rowg * 128 + (l >> 4) * 16;
            a0 = *(const short8*)yr;
            a1 = *(const short8*)(yr + 64);
        }
        __syncthreads();   // cf ready (g2=0) / prev chunk epilogue reads done (g2=1)
        #pragma unroll
        for (int nt = 0; nt < 4; ++nt) {
            f32x4 acc = {0.f, 0.f, 0.f, 0.f};
            acc = __builtin_amdgcn_mfma_f32_16x16x32_bf16(a0, bfr[nt][0], acc, 0, 0, 0);
            acc = __builtin_amdgcn_mfma_f32_16x16x32_bf16(a1, bfr[nt][1], acc, 0, 0, 0);
            const int e = nt * 16 + (l & 15);
            #pragma unroll
            for (int i = 0; i < 4; ++i)
                zs[w * 16 + 4 * (l >> 4) + i][e] = acc[i];
        }
        __syncthreads();

        #pragma unroll
        for (int i = 0; i < 4; ++i) {
            int rloc = i * 16 + (tid >> 4);
            long gr = row0 + rloc;
            int ch0 = (tid & 15) * 4;
            if (gr < M_) {
                uint2 yp = *(const uint2*)((const char*)y + gr * 128 + ch0 * 2);
                float4 z4 = *(const float4*)&zs[rloc][ch0];
                float yv0 = bflo(yp.x), yv1 = bfu((ushort)(yp.x >> 16));
                float yv2 = bflo(yp.y), yv3 = bfu((ushort)(yp.y >> 16));
                float4 o;
                o.x = fmaf(cf[0][ch0 + 0], yv0, cf[1][ch0 + 0]) + gelu_tanh(fmaf(cf[2][ch0 + 0], z4.x, cf[3][ch0 + 0]));
                o.y = fmaf(cf[0][ch0 + 1], yv1, cf[1][ch0 + 1]) + gelu_tanh(fmaf(cf[2][ch0 + 1], z4.y, cf[3][ch0 + 1]));
                o.z = fmaf(cf[0][ch0 + 2], yv2, cf[1][ch0 + 2]) + gelu_tanh(fmaf(cf[2][ch0 + 2], z4.z, cf[3][ch0 + 2]));
                o.w = fmaf(cf[0][ch0 + 3], yv3, cf[1][ch0 + 3]) + gelu_tanh(fmaf(cf[2][ch0 + 3], z4.w, cf[3][ch0 + 3]));
                *(float4*)&out[gr * 64 + ch0] = o;
            }
        }
    }
}

extern "C" void kernel_launch(void* const* d_in, const int* in_sizes, int n_in,
                              void* d_out, int out_size, void* d_ws, size_t ws_size,
                              hipStream_t stream) {
    const float* x       = (const float*)d_in[0];
    const float* weights = (const float*)d_in[1];
    const float* w_conv  = (const float*)d_in[2];
    const float* scale1  = (const float*)d_in[3];
    const float* bias1   = (const float*)d_in[4];
    const float* scale2  = (const float*)d_in[5];
    const float* bias2   = (const float*)d_in[6];
    float* out = (float*)d_out;
    float* ws  = (float*)d_ws;

    ushort* Wb  = (ushort*)(ws + OF_WB);
    ushort* Wb2 = (ushort*)(ws + OF_WB2);
    ushort* yb  = (ushort*)(ws + OF_Y);
    float* ps1 = ws + OF_PS1;
    float* pq1 = ws + OF_PQ1;
    float* ps2 = ws + OF_PS2;
    float* pq2 = ws + OF_PQ2;
    float* A1  = ws + OF_C1;
    float* BB1 = ws + OF_C1 + 64;

    const float invN = 1.f / (float)M_;

    kPb<<<112, 256, 0, stream>>>(weights, Wb);
    kA<<<dim3(NJB, B_), 256, 0, stream>>>(x, Wb, yb, ps1, pq1);
    kB<<<64, 256, 0, stream>>>(ps1, pq1, A1, BB1, scale1, bias1, NBLKA, invN, w_conv, Wb2);
    kZ<<<NBZ, 256, 0, stream>>>(yb, Wb2, ps2, pq2);
    kE<<<NBE, 256, 0, stream>>>(yb, Wb2, A1, BB1, scale2, bias2, ps2, pq2, out);
}

// Round 18
// 55.243 us; speedup vs baseline: 1.2243x; 1.2243x over previous
//
#include <hip/hip_runtime.h>
#include <hip/hip_bf16.h>

#define B_ 4
#define L_ 32768
#define C_ 64
#define K_ 7
#define T_ 16378              // (L - 2K)/2 + 1
#define M_ (B_*T_)            // 65512 rows
#define TJ 16                 // output positions per j-tile
#define IT 4                  // j-tiles per kA block
#define NJB 256               // grid.x of kA  (NJB*IT*TJ = 16384 >= T_)
#define NBLKA (B_*NJB)        // 1024 partial sets
#define NBZ 512               // kZ blocks (x128 rows)
#define NBE 512               // kE blocks (x128 rows)

// workspace layout in floats
#define OF_WB   0                        // Wb: 28672 ushorts = 14336 floats
#define OF_WB2  14336                    // Wb2: 4096 ushorts = 2048 floats
#define OF_Y    16384                    // y bf16: M_*64 ushorts = M_*32 floats
#define OF_PS1  (OF_Y + M_*32)           // [c][NBLKA]
#define OF_PQ1  (OF_PS1 + 64*NBLKA)
#define OF_PS2  (OF_PQ1 + 64*NBLKA)      // [c][NBZ]
#define OF_PQ2  (OF_PS2 + 64*NBZ)
#define OF_C1   (OF_PQ2 + 64*NBZ)        // A1[64], BB1[64]
#define OF_C2   (OF_C1 + 128)            // A2[64], BB2[64]

typedef __attribute__((ext_vector_type(8))) short short8;
typedef __attribute__((ext_vector_type(4))) float f32x4;

__device__ __forceinline__ unsigned cvt_pk_bf16(float a, float b) {
    unsigned r;
    asm("v_cvt_pk_bf16_f32 %0, %1, %2" : "=v"(r) : "v"(a), "v"(b));
    return r;   // lo = bf16(a), hi = bf16(b)
}

__device__ __forceinline__ float fast_tanh(float x) {
    float e = __builtin_amdgcn_exp2f(x * 2.885390082f);   // 2*log2(e)
    return __builtin_fmaf(-2.f, __builtin_amdgcn_rcpf(1.f + e), 1.f);
}

__device__ __forceinline__ float gelu_tanh(float v) {
    float u = 0.7978845608028654f * (v + 0.044715f * v * v * v);
    return 0.5f * v * (1.f + fast_tanh(u));
}

__device__ __forceinline__ float bfu(ushort h) {
    union { unsigned u; float f; } v; v.u = ((unsigned)h) << 16; return v.f;
}
__device__ __forceinline__ float bflo(unsigned p) {
    union { unsigned u; float f; } v; v.u = p << 16; return v.f;
}

// repack weights (d,c,kk) -> B-fragments Wb[(kt*28+nt)*64 + lane][j] (bf16)
__global__ void kPb(const float* __restrict__ w, ushort* __restrict__ Wb) {
    int i = blockIdx.x * 256 + threadIdx.x;   // 28672 total
    if (i < 28672) {
        int j = i & 7;
        int l = (i >> 3) & 63;
        int q = i >> 9;            // kt*28 + nt
        int nt = q % 28, kt = q / 28;
        int k = kt * 32 + 8 * (l >> 4) + j;       // channel c
        int n = nt * 16 + (l & 15);
        int d = n / 7, kk = n - 7 * d;
        Wb[i] = (ushort)(cvt_pk_bf16(w[(d * 64 + k) * 7 + kk], 0.f) & 0xffffu);
    }
}

// fused: dyn-weight GEMM (MFMA) + tanh + taps + residual + BN1 partials.
// BARRIER-FREE: wave w owns channels d in [16w,16w+16); per-wave private LDS.
__global__ __launch_bounds__(256, 4) void kA(const float* __restrict__ x,
                                             const ushort* __restrict__ Wb,
                                             ushort* __restrict__ y,
                                             float* __restrict__ ps,
                                             float* __restrict__ pq) {
    // per-wave: gw[112][72B] (8064 B, 8-aligned rows) ; xpw[22][17]u32 (1496 B)
    __shared__ char sm[4 * 8064 + 4 * 1496];

    const int tid = threadIdx.x;
    const int w = tid >> 6, l = tid & 63;
    char* gw  = sm + w * 8064;
    char* xpw = sm + 4 * 8064 + w * 1496;
    const int b = blockIdx.y;
    const float* xb = x + b * (L_ * 64);

    short8 wreg[7][2];
    #pragma unroll
    for (int i = 0; i < 7; ++i) {
        wreg[i][0] = *(const short8*)&Wb[((7 * w + i) * 64 + l) * 8];
        wreg[i][1] = *(const short8*)&Wb[((28 + 7 * w + i) * 64 + l) * 8];
    }

    const int cl = l & 15, r0 = 4 * (l >> 4);
    const int g = l >> 4, dp = l & 15;
    float S = 0.f, Q = 0.f;

    for (int it = 0; it < IT; ++it) {
        const int jt = blockIdx.x * IT + it;
        const int j0 = jt * TJ;
        const int xrow0 = 2 * j0;
        const bool tail = (jt == NJB * IT - 1);

        // ---- stage tap slice: items = (rowpair rp, channel-pair cp), float2 loads ----
        #pragma unroll
        for (int q = 0; q < 3; ++q) {
            int item = q * 64 + l;             // 0..175 used (22 rp * 8 cp)
            if (q < 2 || l < 48) {
                int rp = item >> 3, cp = item & 7;
                int ra = xrow0 + 2 * rp, rb = ra + 1;
                if (tail) { ra = min(ra, L_ - 1); rb = min(rb, L_ - 1); }
                float2 va = *(const float2*)(xb + ra * 64 + 16 * w + 2 * cp);
                float2 vb = *(const float2*)(xb + rb * 64 + 16 * w + 2 * cp);
                uint2 wv;
                wv.x = cvt_pk_bf16(va.x, vb.x);
                wv.y = cvt_pk_bf16(va.y, vb.y);
                *(uint2*)(xpw + rp * 68 + cp * 8) = wv;
            }
        }

        short8 afr[2][2];
        #pragma unroll
        for (int mt = 0; mt < 2; ++mt)
            #pragma unroll
            for (int kt = 0; kt < 2; ++kt) {
                int row = xrow0 + 12 + mt * 16 + cl;
                if (tail) row = min(row, L_ - 1);
                const float* pr = xb + row * 64 + kt * 32 + (l >> 4) * 8;
                float4 v0 = *(const float4*)pr;
                float4 v1 = *(const float4*)(pr + 4);
                uint4 u;
                u.x = cvt_pk_bf16(v0.x, v0.y);
                u.y = cvt_pk_bf16(v0.z, v0.w);
                u.z = cvt_pk_bf16(v1.x, v1.y);
                u.w = cvt_pk_bf16(v1.z, v1.w);
                afr[mt][kt] = *(short8*)&u;
            }

        #pragma unroll
        for (int i = 0; i < 7; ++i) {
            f32x4 acc0 = {0.f, 0.f, 0.f, 0.f};
            f32x4 acc1 = {0.f, 0.f, 0.f, 0.f};
            acc0 = __builtin_amdgcn_mfma_f32_16x16x32_bf16(afr[0][0], wreg[i][0], acc0, 0, 0, 0);
            acc0 = __builtin_amdgcn_mfma_f32_16x16x32_bf16(afr[0][1], wreg[i][1], acc0, 0, 0, 0);
            acc1 = __builtin_amdgcn_mfma_f32_16x16x32_bf16(afr[1][0], wreg[i][0], acc1, 0, 0, 0);
            acc1 = __builtin_amdgcn_mfma_f32_16x16x32_bf16(afr[1][1], wreg[i][1], acc1, 0, 0, 0);
            char* base = gw + (i * 16 + cl) * 72 + r0 * 2;
            *(unsigned*)(base)      = cvt_pk_bf16(fast_tanh(acc0[0]), fast_tanh(acc0[1]));
            *(unsigned*)(base + 4)  = cvt_pk_bf16(fast_tanh(acc0[2]), fast_tanh(acc0[3]));
            *(unsigned*)(base + 32) = cvt_pk_bf16(fast_tanh(acc1[0]), fast_tanh(acc1[1]));
            *(unsigned*)(base + 36) = cvt_pk_bf16(fast_tanh(acc1[2]), fast_tanh(acc1[3]));
        }

        #pragma unroll
        for (int p = 0; p < 2; ++p) {
            const int jj0 = 2 * g + 8 * p;
            unsigned xv[8];
            #pragma unroll
            for (int k2 = 0; k2 < 8; ++k2)
                xv[k2] = *(const unsigned*)((const char*)xpw + (jj0 + k2) * 68 + dp * 4);
            float acc0 = bflo(xv[6]);
            float acc1 = bflo(xv[7]);
            const char* gb = gw + dp * 504 + jj0 * 4;
            #pragma unroll
            for (int kk = 0; kk < K_; ++kk) {
                uint2 gp = *(const uint2*)(gb + kk * 72);
                asm("v_dot2_f32_bf16 %0, %1, %2, %0" : "+v"(acc0) : "v"(xv[kk]),     "v"(gp.x));
                asm("v_dot2_f32_bf16 %0, %1, %2, %0" : "+v"(acc1) : "v"(xv[kk + 1]), "v"(gp.y));
            }
            float o0 = __shfl_xor(acc0, 1);
            float o1 = __shfl_xor(acc1, 1);
            const int j = j0 + jj0;
            if (j < T_) {
                if ((dp & 1) == 0) {
                    *(unsigned*)((char*)y + (b * T_ + j) * 128 + (16 * w + dp) * 2)     = cvt_pk_bf16(acc0, o0);
                    *(unsigned*)((char*)y + (b * T_ + j + 1) * 128 + (16 * w + dp) * 2) = cvt_pk_bf16(acc1, o1);
                }
                S += acc0 + acc1;
                Q += acc0 * acc0 + acc1 * acc1;
            }
        }
    }

    S += __shfl_xor(S, 16); S += __shfl_xor(S, 32);
    Q += __shfl_xor(Q, 16); Q += __shfl_xor(Q, 32);
    if (l < 16) {
        int d = 16 * w + l;
        int blk = b * NJB + blockIdx.x;
        ps[d * NBLKA + blk] = S;
        pq[d * NBLKA + blk] = Q;
    }
}

// reduce transposed per-channel partials -> A = rstd*scale, BB = bias - mean*A.
// If Wb2 != null, also write this channel's 64 A1-folded w_conv fragments.
__global__ void kB(const float* __restrict__ ps, const float* __restrict__ pq,
                   float* __restrict__ A, float* __restrict__ BB,
                   const float* __restrict__ scale, const float* __restrict__ bias,
                   int nblk, float invN,
                   const float* __restrict__ wconv, ushort* __restrict__ Wb2) {
    const int c = blockIdx.x;
    const float* bs = ps + (long)c * nblk;
    const float* bq = pq + (long)c * nblk;
    float S = 0.f, Q = 0.f;
    for (int i = threadIdx.x; i < nblk; i += 256) {
        S += bs[i];
        Q += bq[i];
    }
    for (int o = 32; o > 0; o >>= 1) {
        S += __shfl_down(S, o);
        Q += __shfl_down(Q, o);
    }
    __shared__ float rs[4], rq[4];
    __shared__ float sa;
    if ((threadIdx.x & 63) == 0) { rs[threadIdx.x >> 6] = S; rq[threadIdx.x >> 6] = Q; }
    __syncthreads();
    if (threadIdx.x == 0) {
        S = rs[0] + rs[1] + rs[2] + rs[3];
        Q = rq[0] + rq[1] + rq[2] + rq[3];
        float m = S * invN;
        float var = Q * invN - m * m;
        float rstd = rsqrtf(var + 1e-5f);
        float a = rstd * scale[c];
        A[c] = a;
        BB[c] = bias[c] - m * a;
        sa = a;
    }
    if (Wb2 != nullptr) {
        __syncthreads();
        if (threadIdx.x < 64) {
            int e = threadIdx.x;
            float wv = sa * wconv[c * 64 + e];
            int kt = c >> 5, rem = c & 31, bslot = rem >> 3, j = rem & 7;
            int lane = bslot * 16 + (e & 15), nt = e >> 4;
            Wb2[(((kt * 4 + nt) * 64 + lane) << 3) + j] =
                (ushort)(cvt_pk_bf16(wv, 0.f) & 0xffffu);
        }
    }
}

// pass 2a: z' = y_bf16 @ Wb2, BN2 partials only — frags from global, no LDS staging
__global__ __launch_bounds__(256) void kZ(const ushort* __restrict__ y,
                                          const ushort* __restrict__ Wb2,
                                          float* __restrict__ ps2,
                                          float* __restrict__ pq2) {
    __shared__ float red[2][4][64];
    const int tid = threadIdx.x, w = tid >> 6, l = tid & 63;
    short8 bfr[4][2];
    #pragma unroll
    for (int nt = 0; nt < 4; ++nt)
        #pragma unroll
        for (int kt = 0; kt < 2; ++kt)
            bfr[nt][kt] = *(const short8*)&Wb2[((kt * 4 + nt) * 64 + l) * 8];

    float ss[4] = {0.f, 0.f, 0.f, 0.f}, qq[4] = {0.f, 0.f, 0.f, 0.f};
    #pragma unroll
    for (int g2 = 0; g2 < 2; ++g2) {
        long rowg = (long)blockIdx.x * 128 + g2 * 64 + w * 16 + (l & 15);
        short8 a0 = {0, 0, 0, 0, 0, 0, 0, 0};
        short8 a1 = {0, 0, 0, 0, 0, 0, 0, 0};
        if (rowg < M_) {
            const char* yr = (const char*)y + rowg * 128 + (l >> 4) * 16;
            a0 = *(const short8*)yr;
            a1 = *(const short8*)(yr + 64);
        }
        #pragma unroll
        for (int nt = 0; nt < 4; ++nt) {
            f32x4 acc = {0.f, 0.f, 0.f, 0.f};
            acc = __builtin_amdgcn_mfma_f32_16x16x32_bf16(a0, bfr[nt][0], acc, 0, 0, 0);
            acc = __builtin_amdgcn_mfma_f32_16x16x32_bf16(a1, bfr[nt][1], acc, 0, 0, 0);
            #pragma unroll
            for (int i = 0; i < 4; ++i) { ss[nt] += acc[i]; qq[nt] += acc[i] * acc[i]; }
        }
    }
    #pragma unroll
    for (int nt = 0; nt < 4; ++nt) {
        float s2 = ss[nt] + __shfl_xor(ss[nt], 16); s2 += __shfl_xor(s2, 32);
        float q2 = qq[nt] + __shfl_xor(qq[nt], 16); q2 += __shfl_xor(q2, 32);
        if (l < 16) { red[0][w][nt * 16 + l] = s2; red[1][w][nt * 16 + l] = q2; }
    }
    __syncthreads();
    if (tid < 64) {
        float S = red[0][0][tid] + red[0][1][tid] + red[0][2][tid] + red[0][3][tid];
        float Q = red[1][0][tid] + red[1][1][tid] + red[1][2][tid] + red[1][3][tid];
        ps2[tid * NBZ + blockIdx.x] = S;
        pq2[tid * NBZ + blockIdx.x] = Q;
    }
}

// pass 2b: recompute z' -> LDS transpose -> coalesced fused epilogue.
// 512 blocks x 128 rows: bfr/cf loaded once, two 64-row chunks per block.
__global__ __launch_bounds__(256) void kE(const ushort* __restrict__ y,
                                          const ushort* __restrict__ Wb2,
                                          const float* __restrict__ A1,
                                          const float* __restrict__ B1,
                                          const float* __restrict__ A2,
                                          const float* __restrict__ B2,
                                          float* __restrict__ out) {
    __shared__ float zs[64][68];     // padded, 17408 B
    __shared__ float cf[4][64];
    const int tid = threadIdx.x, w = tid >> 6, l = tid & 63;

    if (tid < 64)       cf[0][tid] = A1[tid];
    else if (tid < 128) cf[1][tid - 64] = B1[tid - 64];
    else if (tid < 192) cf[2][tid - 128] = A2[tid - 128];
    else                cf[3][tid - 192] = B2[tid - 192];

    short8 bfr[4][2];
    #pragma unroll
    for (int nt = 0; nt < 4; ++nt)
        #pragma unroll
        for (int kt = 0; kt < 2; ++kt)
            bfr[nt][kt] = *(const short8*)&Wb2[((kt * 4 + nt) * 64 + l) * 8];

    #pragma unroll
    for (int g2 = 0; g2 < 2; ++g2) {
        const long row0 = (long)blockIdx.x * 128 + g2 * 64;
        long rowg = row0 + w * 16 + (l & 15);
        short8 a0 = {0, 0, 0, 0, 0, 0, 0, 0};
        short8 a1 = {0, 0, 0, 0, 0, 0, 0, 0};
        if (rowg < M_) {
            const char* yr = (const char*)y + rowg * 128 + (l >> 4) * 16;
            a0 = *(const short8*)yr;
            a1 = *(const short8*)(yr + 64);
        }
        __syncthreads();   // cf ready (g2=0) / prev chunk epilogue reads done (g2=1)
        #pragma unroll
        for (int nt = 0; nt < 4; ++nt) {
            f32x4 acc = {0.f, 0.f, 0.f, 0.f};
            acc = __builtin_amdgcn_mfma_f32_16x16x32_bf16(a0, bfr[nt][0], acc, 0, 0, 0);
            acc = __builtin_amdgcn_mfma_f32_16x16x32_bf16(a1, bfr[nt][1], acc, 0, 0, 0);
            const int e = nt * 16 + (l & 15);
            #pragma unroll
            for (int i = 0; i < 4; ++i)
                zs[w * 16 + 4 * (l >> 4) + i][e] = acc[i];
        }
        __syncthreads();

        #pragma unroll
        for (int i = 0; i < 4; ++i) {
            int rloc = i * 16 + (tid >> 4);
            long gr = row0 + rloc;
            int ch0 = (tid & 15) * 4;
            if (gr < M_) {
                uint2 yp = *(const uint2*)((const char*)y + gr * 128 + ch0 * 2);
                float4 z4 = *(const float4*)&zs[rloc][ch0];
                float yv0 = bflo(yp.x), yv1 = bfu((ushort)(yp.x >> 16));
                float yv2 = bflo(yp.y), yv3 = bfu((ushort)(yp.y >> 16));
                float4 o;
                o.x = fmaf(cf[0][ch0 + 0], yv0, cf[1][ch0 + 0]) + gelu_tanh(fmaf(cf[2][ch0 + 0], z4.x, cf[3][ch0 + 0]));
                o.y = fmaf(cf[0][ch0 + 1], yv1, cf[1][ch0 + 1]) + gelu_tanh(fmaf(cf[2][ch0 + 1], z4.y, cf[3][ch0 + 1]));
                o.z = fmaf(cf[0][ch0 + 2], yv2, cf[1][ch0 + 2]) + gelu_tanh(fmaf(cf[2][ch0 + 2], z4.z, cf[3][ch0 + 2]));
                o.w = fmaf(cf[0][ch0 + 3], yv3, cf[1][ch0 + 3]) + gelu_tanh(fmaf(cf[2][ch0 + 3], z4.w, cf[3][ch0 + 3]));
                *(float4*)&out[gr * 64 + ch0] = o;
            }
        }
    }
}

extern "C" void kernel_launch(void* const* d_in, const int* in_sizes, int n_in,
                              void* d_out, int out_size, void* d_ws, size_t ws_size,
                              hipStream_t stream) {
    const float* x       = (const float*)d_in[0];
    const float* weights = (const float*)d_in[1];
    const float* w_conv  = (const float*)d_in[2];
    const float* scale1  = (const float*)d_in[3];
    const float* bias1   = (const float*)d_in[4];
    const float* scale2  = (const float*)d_in[5];
    const float* bias2   = (const float*)d_in[6];
    float* out = (float*)d_out;
    float* ws  = (float*)d_ws;

    ushort* Wb  = (ushort*)(ws + OF_WB);
    ushort* Wb2 = (ushort*)(ws + OF_WB2);
    ushort* yb  = (ushort*)(ws + OF_Y);
    float* ps1 = ws + OF_PS1;
    float* pq1 = ws + OF_PQ1;
    float* ps2 = ws + OF_PS2;
    float* pq2 = ws + OF_PQ2;
    float* A1  = ws + OF_C1;
    float* BB1 = ws + OF_C1 + 64;
    float* A2  = ws + OF_C2;
    float* BB2 = ws + OF_C2 + 64;

    const float invN = 1.f / (float)M_;

    kPb<<<112, 256, 0, stream>>>(weights, Wb);
    kA<<<dim3(NJB, B_), 256, 0, stream>>>(x, Wb, yb, ps1, pq1);
    kB<<<64, 256, 0, stream>>>(ps1, pq1, A1, BB1, scale1, bias1, NBLKA, invN, w_conv, Wb2);
    kZ<<<NBZ, 256, 0, stream>>>(yb, Wb2, ps2, pq2);
    kB<<<64, 256, 0, stream>>>(ps2, pq2, A2, BB2, scale2, bias2, NBZ, invN, nullptr, nullptr);
    kE<<<NBE, 256, 0, stream>>>(yb, Wb2, A1, BB1, A2, BB2, out);
}